// Round 2
// baseline (10703.214 us; speedup 1.0000x reference)
//
#include <hip/hip_runtime.h>
#include <math.h>
#include <float.h>

#define EPSV 1e-8f
#define MASK_FILL 1000000000.0f
constexpr int D = 64;

// ---------------------------------------------------------------------------
// Kernel 1: normalize codebook rows.
//   cb   = codebook / (||codebook|| + eps)          (natural [K][64] layout)
//   cb_n = cb / (||cb|| + eps)                      (normalized twice, stored
//          tile-transposed: per 64-row tile, [16 float4-groups][64 codes])
// ---------------------------------------------------------------------------
__global__ __launch_bounds__(256) void k_cb(const float* __restrict__ cbin,
                                            float* __restrict__ cb,
                                            float4* __restrict__ cbt) {
    __shared__ float tile[16 * 64 * 4];  // [g][c][4] = 16 KB
    const int t = threadIdx.x;
    const int wv = t >> 6, lane = t & 63;
    const int tileRow0 = blockIdx.x * 64;

    for (int j = 0; j < 16; ++j) {
        const int c = wv * 16 + j;            // code within tile
        const int row = tileRow0 + c;
        float v = cbin[row * D + lane];
        float ss = v * v;
        #pragma unroll
        for (int off = 32; off; off >>= 1) ss += __shfl_xor(ss, off, 64);
        const float n1 = sqrtf(ss);
        const float c1 = v / (n1 + EPSV);
        cb[row * D + lane] = c1;
        float ss2 = c1 * c1;
        #pragma unroll
        for (int off = 32; off; off >>= 1) ss2 += __shfl_xor(ss2, off, 64);
        const float n2 = sqrtf(ss2);
        const float c2 = c1 / (n2 + EPSV);
        // transposed store: float offset (d/4)*256 + c*4 + (d%4)
        tile[(lane >> 2) * 256 + c * 4 + (lane & 3)] = c2;
    }
    __syncthreads();
    float4* dst = cbt + (size_t)blockIdx.x * 1024;
    const float4* srcT = (const float4*)tile;
    #pragma unroll
    for (int i = 0; i < 4; ++i) dst[i * 256 + t] = srcT[i * 256 + t];
}

// ---------------------------------------------------------------------------
// Kernel 2: normalize x rows -> x_n (written straight into d_out region 2)
// ---------------------------------------------------------------------------
__global__ __launch_bounds__(256) void k_x(const float* __restrict__ xin,
                                           float* __restrict__ xn) {
    const int t = threadIdx.x;
    const int wv = t >> 6, lane = t & 63;
    const int row = blockIdx.x * 4 + wv;
    float v = xin[row * D + lane];
    float ss = v * v;
    #pragma unroll
    for (int off = 32; off; off >>= 1) ss += __shfl_xor(ss, off, 64);
    const float n = sqrtf(ss);
    xn[row * D + lane] = v / (n + EPSV);
}

// ---------------------------------------------------------------------------
// Kernel 3: fused  -x_n·cb_n^T  +  mask-fill  +  row argmin  +  gather/outputs
//   block = 256 threads (4 waves), 32 rows/block (8 rows/wave).
//   Register blocking: each lane owns 4 codes per 256-code K-tile
//   (k = tk*256 + ct*64 + lane), so per tile: 2048 FMA vs 192 ds_read_b128.
// ---------------------------------------------------------------------------
__global__ __launch_bounds__(256, 2) void k_main(const float* __restrict__ xn,
                                                 const float4* __restrict__ cbt,
                                                 const float* __restrict__ cb,
                                                 const int* __restrict__ mask,
                                                 const int* __restrict__ training,
                                                 float* __restrict__ out,
                                                 int B, int K) {
    __shared__ float4 cbs[4096];     // 64 KB: [ct (0..3)][g (0..15)][c (0..63)]
    __shared__ float4 xs[512];       // 8 KB:  [row (0..31)][g (0..15)]
    const int t = threadIdx.x;
    const int wv = t >> 6, lane = t & 63;
    const int row0 = blockIdx.x * 32;
    const int tr = training[0];

    // stage this block's 32 x_n rows once
    const float4* x4 = (const float4*)xn + (size_t)row0 * 16;
    xs[t] = x4[t];
    xs[256 + t] = x4[256 + t];

    float best[8];
    int bidx[8];
    #pragma unroll
    for (int r = 0; r < 8; ++r) { best[r] = FLT_MAX; bidx[r] = 0; }

    const int* mbase = mask + (size_t)(row0 + wv * 8) * K;

    const int nT = K / 256;
    for (int tk = 0; tk < nT; ++tk) {
        __syncthreads();   // previous tile's compute done (also covers xs on tk=0)
        const float4* src = cbt + (size_t)tk * 4096;
        #pragma unroll
        for (int i = 0; i < 16; ++i) cbs[i * 256 + t] = src[i * 256 + t];
        __syncthreads();   // cbs staged

        // issue mask loads now; consumed after the FMA loop (hidden under it)
        int m[8][4];
        const int kb = tk * 256 + lane;
        #pragma unroll
        for (int r = 0; r < 8; ++r)
            #pragma unroll
            for (int ct = 0; ct < 4; ++ct)
                m[r][ct] = mbase[(size_t)r * K + ct * 64 + kb];

        float sim[8][4];
        #pragma unroll
        for (int r = 0; r < 8; ++r)
            #pragma unroll
            for (int ct = 0; ct < 4; ++ct) sim[r][ct] = 0.f;

        #pragma unroll
        for (int g = 0; g < 16; ++g) {
            float4 xv[8];
            #pragma unroll
            for (int r = 0; r < 8; ++r) xv[r] = xs[(wv * 8 + r) * 16 + g];
            #pragma unroll
            for (int ct = 0; ct < 4; ++ct) {
                const float4 cv = cbs[ct * 1024 + g * 64 + lane];
                #pragma unroll
                for (int r = 0; r < 8; ++r) {
                    sim[r][ct] = fmaf(xv[r].x, cv.x, sim[r][ct]);
                    sim[r][ct] = fmaf(xv[r].y, cv.y, sim[r][ct]);
                    sim[r][ct] = fmaf(xv[r].z, cv.z, sim[r][ct]);
                    sim[r][ct] = fmaf(xv[r].w, cv.w, sim[r][ct]);
                }
            }
        }

        #pragma unroll
        for (int r = 0; r < 8; ++r)
            #pragma unroll
            for (int ct = 0; ct < 4; ++ct) {
                const int k = tk * 256 + ct * 64 + lane;
                const float dist = (m[r][ct] != 0 || tr == 0) ? -sim[r][ct] : MASK_FILL;
                if (dist < best[r]) { best[r] = dist; bidx[r] = k; }  // first-min kept
            }
    }

    float* out_zq  = out;
    float* out_z   = out + (size_t)B * D;
    float* out_idx = out + (size_t)3 * B * D;
    const float* xsf = (const float*)xs;

    #pragma unroll
    for (int r = 0; r < 8; ++r) {
        const int lrow = wv * 8 + r;
        float b = best[r];
        int bi = bidx[r];
        #pragma unroll
        for (int off = 32; off; off >>= 1) {
            const float ob = __shfl_xor(b, off, 64);
            const int   oi = __shfl_xor(bi, off, 64);
            if (ob < b || (ob == b && oi < bi)) { b = ob; bi = oi; }
        }
        const int grow = row0 + lrow;
        const float zv  = cb[(size_t)bi * D + lane];
        const float xnv = xsf[lrow * 64 + lane];
        const float zq  = xnv + (zv - xnv);   // literal straight-through math
        out_zq[(size_t)grow * D + lane] = zq;
        out_z [(size_t)grow * D + lane] = zv;
        if (lane == 0) out_idx[grow] = (float)bi;
    }
}

extern "C" void kernel_launch(void* const* d_in, const int* in_sizes, int n_in,
                              void* d_out, int out_size, void* d_ws, size_t ws_size,
                              hipStream_t stream) {
    const float* x    = (const float*)d_in[0];
    const float* cbin = (const float*)d_in[1];
    const int* mask   = (const int*)d_in[2];
    const int* train  = (const int*)d_in[3];
    const int B = in_sizes[0] / D;   // 16384
    const int K = in_sizes[1] / D;   // 16384
    float* out = (float*)d_out;

    float*  cb  = (float*)d_ws;                                   // K*64 f32 = 4 MB
    float4* cbt = (float4*)((char*)d_ws + (size_t)K * D * 4);     // 4 MB, tiled-transposed

    float* out_xn = out + (size_t)2 * B * D;

    k_cb  <<<K / 64, 256, 0, stream>>>(cbin, cb, cbt);
    k_x   <<<B / 4,  256, 0, stream>>>(x, out_xn);
    k_main<<<B / 32, 256, 0, stream>>>(out_xn, cbt, cb, mask, train, out, B, K);
}

// Round 3
// 699.592 us; speedup vs baseline: 15.2992x; 15.2992x over previous
//
#include <hip/hip_runtime.h>
#include <math.h>
#include <float.h>

#define EPSV 1e-8f
#define MASK_FILL 1000000000.0f
constexpr int D = 64;

typedef __attribute__((ext_vector_type(16))) float f32x16;

// component d (compile-time) of the cv[16] float4 register array
#define CVF(d) (((d) & 3) == 0 ? cv[(d) >> 2].x : \
                ((d) & 3) == 1 ? cv[(d) >> 2].y : \
                ((d) & 3) == 2 ? cv[(d) >> 2].z : cv[(d) >> 2].w)

// ---------------------------------------------------------------------------
// Kernel 1: normalize codebook rows.
//   cb   = codebook/(||codebook||+eps)   natural [K][64] (for the gather)
//   cbt  = cb/(||cb||+eps) stored PRE-SWIZZLED per 64-code tile:
//          float4 slot  tile*1024 + c*16 + (g ^ (c&7)),  g = dim/4
//          so a linear global_load_lds stage yields the bank-balanced layout.
// ---------------------------------------------------------------------------
__global__ __launch_bounds__(256) void k_cb(const float* __restrict__ cbin,
                                            float* __restrict__ cb,
                                            float* __restrict__ cbtf) {
    const int t = threadIdx.x;
    const int wv = t >> 6, lane = t & 63;       // lane = dim
    const int tile = blockIdx.x;
    const int g = lane >> 2, comp = lane & 3;
    for (int j = 0; j < 16; ++j) {
        const int c = wv * 16 + j;              // code within tile
        const int row = tile * 64 + c;
        float v = cbin[row * D + lane];
        float ss = v * v;
        #pragma unroll
        for (int off = 32; off; off >>= 1) ss += __shfl_xor(ss, off, 64);
        const float c1 = v / (sqrtf(ss) + EPSV);
        cb[row * D + lane] = c1;
        float ss2 = c1 * c1;
        #pragma unroll
        for (int off = 32; off; off >>= 1) ss2 += __shfl_xor(ss2, off, 64);
        const float c2 = c1 / (sqrtf(ss2) + EPSV);
        cbtf[((size_t)tile * 1024 + c * 16 + (g ^ (c & 7))) * 4 + comp] = c2;
    }
}

// ---------------------------------------------------------------------------
// Kernel 2: normalize x rows -> x_n (written straight into d_out region 2)
// ---------------------------------------------------------------------------
__global__ __launch_bounds__(256) void k_x(const float* __restrict__ xin,
                                           float* __restrict__ xn) {
    const int t = threadIdx.x;
    const int wv = t >> 6, lane = t & 63;
    const int row = blockIdx.x * 4 + wv;
    float v = xin[row * D + lane];
    float ss = v * v;
    #pragma unroll
    for (int off = 32; off; off >>= 1) ss += __shfl_xor(ss, off, 64);
    xn[row * D + lane] = v / (sqrtf(ss) + EPSV);
}

// ---------------------------------------------------------------------------
// Kernel 3: distance scan. lane<->code, 8 rows/wave, K-split 2.
//   cb tile: 64 VGPRs/lane via swizzled ds_read_b128 (reused for 8 rows)
//   x row  : 64 SGPRs via s_load_dwordx16 x4 (scalar pipe, off the LDS pipe)
//   writes per-half (dist, idx) partials to workspace
// ---------------------------------------------------------------------------
__global__ __launch_bounds__(256, 3) void k_main(const float* __restrict__ xn,
                                                 const float4* __restrict__ cbt,
                                                 const int* __restrict__ mask,
                                                 const int* __restrict__ training,
                                                 float* __restrict__ pd,
                                                 int* __restrict__ pi,
                                                 int B, int K) {
    __shared__ float4 buf[2][1024];   // 2 x 16 KB double buffer
    const int t = threadIdx.x;
    const int wv = t >> 6, lane = t & 63;
    const int half = blockIdx.x & 1;
    const int row0 = (blockIdx.x >> 1) * 32;
    const int tr = training[0];
    const int w8 = lane & 7;
    const int nt = (K / 2) / 64;               // 128 tiles per half
    const int t0 = half * nt;

#define STAGE(bsel, tile_) do {                                                   \
    const float4* gs_ = cbt + (size_t)(tile_) * 1024 + t;                         \
    __builtin_amdgcn_global_load_lds(                                             \
        (const __attribute__((address_space(1))) void*)(gs_),                     \
        (__attribute__((address_space(3))) void*)(&buf[bsel][wv * 64]), 16, 0, 0);\
    __builtin_amdgcn_global_load_lds(                                             \
        (const __attribute__((address_space(1))) void*)(gs_ + 256),               \
        (__attribute__((address_space(3))) void*)(&buf[bsel][256 + wv * 64]), 16, 0, 0);\
    __builtin_amdgcn_global_load_lds(                                             \
        (const __attribute__((address_space(1))) void*)(gs_ + 512),               \
        (__attribute__((address_space(3))) void*)(&buf[bsel][512 + wv * 64]), 16, 0, 0);\
    __builtin_amdgcn_global_load_lds(                                             \
        (const __attribute__((address_space(1))) void*)(gs_ + 768),               \
        (__attribute__((address_space(3))) void*)(&buf[bsel][768 + wv * 64]), 16, 0, 0);\
} while (0)

    const int wvu = __builtin_amdgcn_readfirstlane(wv);
    const float* xwave = xn + (size_t)(row0 + wvu * 8) * 64;   // scalar row base
    const int* mwave = mask + (size_t)(row0 + wv * 8) * K + lane;

    float best[8];
    int bidx[8];
    #pragma unroll
    for (int r = 0; r < 8; ++r) { best[r] = FLT_MAX; bidx[r] = 0; }

    STAGE(0, t0);
    int cur = 0;
    for (int tt = 0; tt < nt; ++tt) {
        __syncthreads();                        // drains vmcnt -> buf[cur] ready
        if (tt + 1 < nt) STAGE(cur ^ 1, t0 + tt + 1);

        const int gk = (t0 + tt) * 64;          // global code base of this tile
        int m[8];
        #pragma unroll
        for (int r = 0; r < 8; ++r) m[r] = mwave[(size_t)r * K + gk];

        float4 cv[16];
        const float4* bp = buf[cur] + lane * 16;
        #pragma unroll
        for (int g = 0; g < 16; ++g) cv[g] = bp[g ^ w8];   // swizzled read

        const int kk = gk + lane;
        #pragma unroll
        for (int r = 0; r < 8; ++r) {
            f32x16 x0, x1, x2, x3;
            const float* xp = xwave + r * 64;
            asm volatile(
                "s_load_dwordx16 %0, %4, 0x0\n\t"
                "s_load_dwordx16 %1, %4, 0x40\n\t"
                "s_load_dwordx16 %2, %4, 0x80\n\t"
                "s_load_dwordx16 %3, %4, 0xc0\n\t"
                "s_waitcnt lgkmcnt(0)"
                : "=&s"(x0), "=&s"(x1), "=&s"(x2), "=&s"(x3)
                : "s"(xp));
            float s0 = 0.f, s1 = 0.f;
            #pragma unroll
            for (int j = 0; j < 16; ++j) s0 = fmaf(x0[j], CVF(j), s0);
            #pragma unroll
            for (int j = 0; j < 16; ++j) s0 = fmaf(x1[j], CVF(16 + j), s0);
            #pragma unroll
            for (int j = 0; j < 16; ++j) s1 = fmaf(x2[j], CVF(32 + j), s1);
            #pragma unroll
            for (int j = 0; j < 16; ++j) s1 = fmaf(x3[j], CVF(48 + j), s1);
            const float sim = s0 + s1;
            const float dist = (m[r] != 0 || tr == 0) ? -sim : MASK_FILL;
            if (dist < best[r]) { best[r] = dist; bidx[r] = kk; }  // first-min
        }
        cur ^= 1;
    }

    #pragma unroll
    for (int r = 0; r < 8; ++r) {
        float b = best[r];
        int bi = bidx[r];
        #pragma unroll
        for (int off = 32; off; off >>= 1) {
            const float ob = __shfl_xor(b, off, 64);
            const int   oi = __shfl_xor(bi, off, 64);
            if (ob < b || (ob == b && oi < bi)) { b = ob; bi = oi; }
        }
        if (lane == 0) {
            const int grow = row0 + wv * 8 + r;
            pd[(size_t)half * B + grow] = b;
            pi[(size_t)half * B + grow] = bi;
        }
    }
#undef STAGE
}

// ---------------------------------------------------------------------------
// Kernel 4: combine the two K-halves, gather z, write zq/z/indices
// ---------------------------------------------------------------------------
__global__ __launch_bounds__(256) void k_reduce(const float* __restrict__ xn,
                                                const float* __restrict__ cb,
                                                const float* __restrict__ pd,
                                                const int* __restrict__ pi,
                                                float* __restrict__ out, int B) {
    const int t = threadIdx.x;
    const int wv = t >> 6, lane = t & 63;
    const int row = blockIdx.x * 4 + wv;
    const float d0 = pd[row], d1 = pd[B + row];
    const int   i0 = pi[row], i1 = pi[B + row];
    const int   bi = (d1 < d0) ? i1 : i0;      // tie -> half 0 (lower index)
    const float zv  = cb[(size_t)bi * D + lane];
    const float xnv = xn[(size_t)row * D + lane];
    const float zq  = xnv + (zv - xnv);        // literal straight-through math
    float* out_zq  = out;
    float* out_z   = out + (size_t)B * D;
    float* out_idx = out + (size_t)3 * B * D;
    out_zq[(size_t)row * D + lane] = zq;
    out_z [(size_t)row * D + lane] = zv;
    if (lane == 0) out_idx[row] = (float)bi;
}

extern "C" void kernel_launch(void* const* d_in, const int* in_sizes, int n_in,
                              void* d_out, int out_size, void* d_ws, size_t ws_size,
                              hipStream_t stream) {
    const float* x    = (const float*)d_in[0];
    const float* cbin = (const float*)d_in[1];
    const int* mask   = (const int*)d_in[2];
    const int* train  = (const int*)d_in[3];
    const int B = in_sizes[0] / D;   // 16384
    const int K = in_sizes[1] / D;   // 16384
    float* out = (float*)d_out;

    float* ws   = (float*)d_ws;
    float* cb   = ws;                              // K*64 f32 = 4 MB
    float* cbtf = ws + (size_t)K * D;              // 4 MB, pre-swizzled tiles
    float* pd   = ws + (size_t)2 * K * D;          // 2*B floats = 128 KB
    int*   pi   = (int*)(ws + (size_t)2 * K * D + 2 * B);

    float* out_xn = out + (size_t)2 * B * D;

    k_cb    <<<K / 64, 256, 0, stream>>>(cbin, cb, cbtf);
    k_x     <<<B / 4,  256, 0, stream>>>(x, out_xn);
    k_main  <<<(B / 32) * 2, 256, 0, stream>>>(out_xn, (const float4*)cbtf, mask,
                                               train, pd, pi, B, K);
    k_reduce<<<B / 4,  256, 0, stream>>>(out_xn, cb, pd, pi, out, B);
}